// Round 7
// baseline (55044.495 us; speedup 1.0000x reference)
//
#include <hip/hip_runtime.h>
#include <hip/hip_bf16.h>
#include <hip/hip_fp16.h>
#include <math.h>

#define BB 64
#define CDIM 512
#define TT 1024
#define HID 256
#define NEMB 30
#define GDIM 768

typedef _Float16 v2h __attribute__((ext_vector_type(2)));

struct TanhC { float c[7]; };

__device__ inline float f_dot2(v2h a, v2h b, float c) {
  return __builtin_amdgcn_fdot2(a, b, c, false);
}
__device__ inline v2h u2v(unsigned u) { return __builtin_bit_cast(v2h, u); }
__device__ inline unsigned v2u(v2h h) { return __builtin_bit_cast(unsigned, h); }
__device__ inline unsigned packh2(float a, float b) {
  v2h t = {(_Float16)a, (_Float16)b};
  return v2u(t);
}
__device__ inline v2h v2splat(float f) {
  _Float16 h = (_Float16)f;
  v2h r = {h, h};
  return r;
}

// input loader: isb=1 -> bf16, else f32
__device__ inline float ldin(const void* p, long i, int isb) {
  if (isb) {
    unsigned u = ((const unsigned short*)p)[i];
    return __uint_as_float(u << 16);
  }
  return ((const float*)p)[i];
}

template <int CTRL, int RM, int BM, bool BC>
__device__ inline float dpp_add(float v) {
  int m = __builtin_amdgcn_update_dpp(0, __builtin_bit_cast(int, v), CTRL, RM, BM, BC);
  return v + __builtin_bit_cast(float, m);
}
__device__ inline float wave_sum64(float v) {
  v = dpp_add<0x111, 0xf, 0xf, true>(v);
  v = dpp_add<0x112, 0xf, 0xf, true>(v);
  v = dpp_add<0x114, 0xf, 0xe, false>(v);
  v = dpp_add<0x118, 0xf, 0xc, false>(v);
  v = dpp_add<0x142, 0xa, 0xf, false>(v);
  v = dpp_add<0x143, 0xc, 0xf, false>(v);
  return v;
}

// ---------------- dtype sniffer ----------------
__global__ void k_sniff(const void* fea, int* flag) {
  __shared__ int s[256];
  int tid = threadIdx.x;
  const unsigned short* u16 = (const unsigned short*)fea;
  int cnt = 0;
  for (int i = tid; i < 2048; i += 256) {
    unsigned u = u16[2 * i];
    float v = __uint_as_float(u << 16);
    float a = fabsf(v);
    if (a > 1e-6f && a < 16.0f) cnt++;
  }
  s[tid] = cnt;
  __syncthreads();
  for (int off = 128; off > 0; off >>= 1) {
    if (tid < off) s[tid] += s[tid + off];
    __syncthreads();
  }
  if (tid == 0) flag[0] = (s[0] > 1024) ? 1 : 0;
}

__global__ void k_cvt_f(const void* src, float* dst, long n, const int* flag) {
  int isb = flag[0];
  long i = (long)blockIdx.x * blockDim.x + threadIdx.x;
  long stride = (long)gridDim.x * blockDim.x;
  for (; i < n; i += stride) dst[i] = ldin(src, i, isb);
}

// Wc2[cp][col]: pair-rows of [i2h (cols 0-255) | Wih[:512] (cols 256-1023)], half2 bits
__global__ void k_wc(const void* i2h, const void* wih, unsigned* wc2, const int* flag) {
  int isb = flag[0];
  int idx = blockIdx.x * 256 + threadIdx.x;  // 1024 blocks
  int cp = idx >> 10, col = idx & 1023;
  float a, b;
  if (col < 256) {
    a = ldin(i2h, (long)(2 * cp) * 256 + col, isb);
    b = ldin(i2h, (long)(2 * cp + 1) * 256 + col, isb);
  } else {
    int j = col - 256;
    a = ldin(wih, (long)(2 * cp) * GDIM + j, isb);
    b = ldin(wih, (long)(2 * cp + 1) * GDIM + j, isb);
  }
  wc2[idx] = packh2(a, b);
}

// w4t[col][l]: TRANSPOSED pair-rows of [h2h (cols 0-255) | whh (cols 256-1023)]
// w4t[col*128 + l] = (W[2l][col], W[2l+1][col])
__global__ void k_w4t(const void* h2hw, const void* whhw, unsigned* w4t, const int* flag) {
  int isb = flag[0];
  int idx = blockIdx.x * 256 + threadIdx.x;  // 512 blocks -> 131072
  int col = idx >> 7, l = idx & 127;
  float a, b2;
  if (col < 256) {
    a = ldin(h2hw, (long)(2 * l) * 256 + col, isb);
    b2 = ldin(h2hw, (long)(2 * l + 1) * 256 + col, isb);
  } else {
    int j = col - 256;
    a = ldin(whhw, (long)(2 * l) * GDIM + j, isb);
    b2 = ldin(whhw, (long)(2 * l + 1) * GDIM + j, isb);
  }
  w4t[idx] = packh2(a, b2);
}

__global__ void k_bias4(const void* h2hb, const void* bhh, float* bias4, const int* flag) {
  int isb = flag[0];
  int col = blockIdx.x * 256 + threadIdx.x;  // 4 blocks
  bias4[col] = (col < 256) ? ldin(h2hb, col, isb) : ldin(bhh, col - 256, isb);
}

// embb[e][col] = Wih[512+e][col] + b_ih[col]
__global__ void k_embb(const void* wih, const void* bih, float* embb, const int* flag) {
  int isb = flag[0];
  int idx = blockIdx.x * 256 + threadIdx.x;  // 90 blocks
  if (idx >= NEMB * GDIM) return;
  int e = idx / GDIM, col = idx % GDIM;
  embb[idx] = ldin(wih, (long)(512 + e) * GDIM + col, isb) + ldin(bih, col, isb);
}

// combined output head
__global__ void k_comb(const void* sg1w, const void* sg1b, const void* sg2w, const void* sg2b,
                       const void* lg1w, const void* lg1b, const void* lg2w, const void* lg2b,
                       float* comb_w, float* comb_b, const int* flag) {
  int isb = flag[0];
  int tid = threadIdx.x;
  float acc[34];
#pragma unroll
  for (int o = 0; o < 34; ++o) acc[o] = 0.f;
  for (int m = 0; m < HID; ++m) {
    float s1 = ldin(sg1w, (long)tid * HID + m, isb);
    float l1 = ldin(lg1w, (long)tid * HID + m, isb);
#pragma unroll
    for (int o = 0; o < 30; ++o) acc[o] += s1 * ldin(sg2w, (long)m * NEMB + o, isb);
#pragma unroll
    for (int o = 0; o < 4; ++o) acc[30 + o] += l1 * ldin(lg2w, (long)m * 4 + o, isb);
  }
  for (int o = 0; o < 34; ++o) comb_w[tid * 34 + o] = acc[o];
  if (tid < 34) {
    float a = 0.f;
    if (tid < 30) {
      for (int m = 0; m < HID; ++m) a += ldin(sg1b, m, isb) * ldin(sg2w, (long)m * NEMB + tid, isb);
      a += ldin(sg2b, tid, isb);
    } else {
      int o = tid - 30;
      for (int m = 0; m < HID; ++m) a += ldin(lg1b, m, isb) * ldin(lg2w, (long)m * 4 + o, isb);
      a += ldin(lg2b, o, isb);
    }
    comb_b[tid] = a;
  }
}

// ---------------- tiled GEMM: C[b][t][col] = fea[b][:,t] . Wc[:,col] ----------------
// col<256 -> pp[b][tp][col] ; col>=256 -> fw2[b][tp][col-256]   (both t-pair-major)
__global__ __launch_bounds__(256) void k_gemm(const void* fea, const unsigned* wc2,
                                              unsigned* pp, unsigned* fw2, const int* flag) {
  const int isb = flag[0];
  const int blk = blockIdx.x;
  const int b = blk >> 6;
  const int tt = (blk >> 3) & 7;
  const int cc = blk & 7;
  const int t0 = tt * 128, c0 = cc * 128;
  __shared__ __align__(16) unsigned At[32][136];
  __shared__ __align__(16) unsigned Wt[32][136];
  const int tid = threadIdx.x;
  const int cp_l = tid >> 3, sg = tid & 7;
  const int tm = tid & 15, tn = tid >> 4;
  float acc[8][8];
#pragma unroll
  for (int i = 0; i < 8; ++i)
#pragma unroll
    for (int jj = 0; jj < 8; ++jj) acc[i][jj] = 0.f;

  for (int kt = 0; kt < 8; ++kt) {
    const int crow = (kt * 32 + cp_l) * 2;
    if (isb) {
      const unsigned short* f0p =
          (const unsigned short*)fea + ((long)b * CDIM + crow) * TT + t0 + sg * 16;
      const unsigned short* f1p = f0p + TT;
#pragma unroll
      for (int q = 0; q < 2; ++q) {
        ushort4 u0a = ((const ushort4*)f0p)[2 * q];
        ushort4 u0b = ((const ushort4*)f0p)[2 * q + 1];
        ushort4 u1a = ((const ushort4*)f1p)[2 * q];
        ushort4 u1b = ((const ushort4*)f1p)[2 * q + 1];
        unsigned short a0[8] = {u0a.x, u0a.y, u0a.z, u0a.w, u0b.x, u0b.y, u0b.z, u0b.w};
        unsigned short a1[8] = {u1a.x, u1a.y, u1a.z, u1a.w, u1b.x, u1b.y, u1b.z, u1b.w};
#pragma unroll
        for (int e = 0; e < 8; ++e) {
          float f0 = __uint_as_float(((unsigned)a0[e]) << 16);
          float f1 = __uint_as_float(((unsigned)a1[e]) << 16);
          At[cp_l][sg * 16 + q * 8 + e] = packh2(f0, f1);
        }
      }
    } else {
      const float* f0p = (const float*)fea + ((long)b * CDIM + crow) * TT + t0 + sg * 16;
      const float* f1p = f0p + TT;
#pragma unroll
      for (int q = 0; q < 4; ++q) {
        float4 v0 = ((const float4*)f0p)[q];
        float4 v1 = ((const float4*)f1p)[q];
        At[cp_l][sg * 16 + q * 4 + 0] = packh2(v0.x, v1.x);
        At[cp_l][sg * 16 + q * 4 + 1] = packh2(v0.y, v1.y);
        At[cp_l][sg * 16 + q * 4 + 2] = packh2(v0.z, v1.z);
        At[cp_l][sg * 16 + q * 4 + 3] = packh2(v0.w, v1.w);
      }
    }
    {
      const uint4* wp = (const uint4*)(wc2 + (long)(kt * 32 + cp_l) * 1024 + c0 + sg * 16);
#pragma unroll
      for (int q = 0; q < 4; ++q) {
        uint4 w = wp[q];
        Wt[cp_l][sg * 16 + q * 4 + 0] = w.x;
        Wt[cp_l][sg * 16 + q * 4 + 1] = w.y;
        Wt[cp_l][sg * 16 + q * 4 + 2] = w.z;
        Wt[cp_l][sg * 16 + q * 4 + 3] = w.w;
      }
    }
    __syncthreads();
    for (int cp = 0; cp < 32; ++cp) {
      uint4 aq0 = *(const uint4*)&At[cp][tm * 4];
      uint4 aq1 = *(const uint4*)&At[cp][64 + tm * 4];
      uint4 bq0 = *(const uint4*)&Wt[cp][tn * 4];
      uint4 bq1 = *(const uint4*)&Wt[cp][64 + tn * 4];
      unsigned av[8] = {aq0.x, aq0.y, aq0.z, aq0.w, aq1.x, aq1.y, aq1.z, aq1.w};
      unsigned bv[8] = {bq0.x, bq0.y, bq0.z, bq0.w, bq1.x, bq1.y, bq1.z, bq1.w};
#pragma unroll
      for (int ti = 0; ti < 8; ++ti)
#pragma unroll
        for (int ci = 0; ci < 8; ++ci)
          acc[ti][ci] = f_dot2(u2v(av[ti]), u2v(bv[ci]), acc[ti][ci]);
    }
    __syncthreads();
  }

#pragma unroll
  for (int q = 0; q < 2; ++q) {
    const int tq = t0 + q * 64 + tm * 4;
#pragma unroll
    for (int pr = 0; pr < 2; ++pr) {
      const int tp = (tq >> 1) + pr;
      const int r0 = q * 4 + 2 * pr, r1 = r0 + 1;
      unsigned* row;
      if (cc < 2)
        row = pp + ((long)b * 512 + tp) * 256 + c0 + tn * 4;
      else
        row = fw2 + ((long)b * 512 + tp) * GDIM + (c0 - 256) + tn * 4;
      uint4 pa = {packh2(acc[r0][0], acc[r1][0]), packh2(acc[r0][1], acc[r1][1]),
                  packh2(acc[r0][2], acc[r1][2]), packh2(acc[r0][3], acc[r1][3])};
      uint4 pb = {packh2(acc[r0][4], acc[r1][4]), packh2(acc[r0][5], acc[r1][5]),
                  packh2(acc[r0][6], acc[r1][6]), packh2(acc[r0][7], acc[r1][7])};
      *(uint4*)row = pa;
      *(uint4*)(row + 64) = pb;
    }
  }
}

// ---------------- cooperative main v3: 256 blocks (4/batch) x 1024 threads ----------------
__global__ __launch_bounds__(1024, 4) void k_main_c3(
    const unsigned* pp, const unsigned* fw2, const int* targets, const unsigned* w4t,
    const float* bias4, const float* embb, const float* scoref, const float* comb_w,
    const float* comb_b, void* out, const int* flag, int steps, TanhC tc, int* bar1, float* Sx,
    float* ghxx, float* gxpx) {
  const int tid = threadIdx.x;
  const int g = blockIdx.x & 63;  // batch
  const int j = blockIdx.x >> 6;  // 0..3 within group
  const int lane = tid & 63, wid = tid >> 6;
  const int isb = flag[0];

  __shared__ __align__(16) float sh_pa[3072];  // A partials / B eb / D' partials
  __shared__ unsigned sh_phsc[264];            // swizzled (ph,score): idx=(h>>5)*33+(h&31)
  __shared__ unsigned sh_alpha2[128];          // unnormalized p pairs (f16)
  __shared__ float sh_hidden[HID];
  __shared__ unsigned sh_h2[128];
  __shared__ float sh_red[4];

  float my_sc = (tid < HID) ? scoref[tid] : 0.f;
  if (tid < HID) sh_hidden[tid] = 0.f;
  if (tid < 128) sh_h2[tid] = 0u;
  __syncthreads();

  const v2h C0 = v2splat(tc.c[0]), C1 = v2splat(tc.c[1]), C2 = v2splat(tc.c[2]),
            C3 = v2splat(tc.c[3]), C4 = v2splat(tc.c[4]), C5 = v2splat(tc.c[5]),
            C6 = v2splat(tc.c[6]);
  const v2h CLO = v2splat(-3.9f), CHI = v2splat(3.9f);
  const v2h VS = v2splat(0.0625f);

  const unsigned* ppbase = pp + ((long)g * 512 + j * 128) * 256;
  const unsigned* fwbase = fw2 + ((long)g * 512 + j * 128) * GDIM;

  // D' mapping (fixed per thread)
  const int dsub = (tid < 768) ? tid / 192 : 0;
  const int dcg = (tid < 768) ? tid % 192 : 0;
  const uint4* frbase = (const uint4*)(fwbase + (long)(dsub * 32) * GDIM) + dcg;

  // B mapping
  const int btp = tid >> 3, bhc = tid & 7;
  const uint4* prow = (const uint4*)(ppbase + (long)btp * 256) + bhc * 8;

  // A mapping (w4t: [col*128 + l] contiguous in l)
  const int achunk = tid >> 8, acol = tid & 255;
  const uint4* awp = (const uint4*)(w4t + (long)acol * 128 + achunk * 32);
  const int gch = (tid < 768) ? tid / 192 : 0;
  const int gcl = (tid < 768) ? tid % 192 : 0;
  const int gcol = 256 + j * 192 + gcl;
  const uint4* gwp = (const uint4*)(w4t + (long)gcol * 128 + gch * 32);

  for (int step = 0; step < steps; ++step) {
    const int tgt = targets[g * steps + step];
    const int par = step & 1;
    float* S_cur = Sx + par * 256;
    float* ghx_cur = ghxx + (long)par * 64 * GDIM;
    float* gxp_cur = gxpx + (long)par * 64 * 4 * GDIM;

    // ---- deep prefetch: B's pp rows + D' chunk 0 (256 B/thread in flight) ----
    uint4 pw[8];
#pragma unroll
    for (int q = 0; q < 8; ++q) pw[q] = prow[q];
    uint4 cur[8];
#pragma unroll
    for (int i = 0; i < 8; ++i) cur[i] = frbase[(long)i * 192];

    // ---- A: ph (256 cols, replicated) + gh slice j (192 cols); contiguous w4t loads ----
    {
      uint4 wv[8];
#pragma unroll
      for (int q = 0; q < 8; ++q) wv[q] = awp[q];
      float a = 0.f;
#pragma unroll
      for (int q = 0; q < 8; ++q) {
        unsigned we[4] = {wv[q].x, wv[q].y, wv[q].z, wv[q].w};
#pragma unroll
        for (int e = 0; e < 4; ++e)
          a = f_dot2(u2v(sh_h2[achunk * 32 + q * 4 + e]), u2v(we[e]), a);
      }
      sh_pa[achunk * 256 + acol] = a;
    }
    if (tid < 768) {
      uint4 wv[8];
#pragma unroll
      for (int q = 0; q < 8; ++q) wv[q] = gwp[q];
      float a = 0.f;
#pragma unroll
      for (int q = 0; q < 8; ++q) {
        unsigned we[4] = {wv[q].x, wv[q].y, wv[q].z, wv[q].w};
#pragma unroll
        for (int e = 0; e < 4; ++e)
          a = f_dot2(u2v(sh_h2[gch * 32 + q * 4 + e]), u2v(we[e]), a);
      }
      sh_pa[1024 + gch * 192 + gcl] = a;
    }
    __syncthreads();
    if (tid < 256) {
      float ph = sh_pa[tid] + sh_pa[256 + tid] + sh_pa[512 + tid] + sh_pa[768 + tid] + bias4[tid];
      sh_phsc[(tid >> 5) * 33 + (tid & 31)] = packh2(ph, my_sc);
    } else if (tid < 448) {
      int cl = tid - 256;
      float gv = sh_pa[1024 + cl] + sh_pa[1024 + 192 + cl] + sh_pa[1024 + 384 + cl] +
                 sh_pa[1024 + 576 + cl] + bias4[256 + j * 192 + cl];
      ghx_cur[(long)g * GDIM + j * 192 + cl] = gv;
    }
    __syncthreads();

    // ---- B: e partials from preloaded pw ----
    {
      v2h acc = v2splat(0.f);
#pragma unroll
      for (int q = 0; q < 8; ++q) {
        unsigned we[4] = {pw[q].x, pw[q].y, pw[q].z, pw[q].w};
#pragma unroll
        for (int e = 0; e < 4; ++e) {
          int hl = q * 4 + e;
          v2h ps = u2v(sh_phsc[bhc * 33 + hl]);
          v2h phb = {ps.x, ps.x};
          v2h scb = {ps.y, ps.y};
          v2h x = u2v(we[e]) + phb;
          x = __builtin_elementwise_max(x, CLO);
          x = __builtin_elementwise_min(x, CHI);
          v2h v = x * x * VS;
          v2h p = C6;
          p = p * v + C5;
          p = p * v + C4;
          p = p * v + C3;
          p = p * v + C2;
          p = p * v + C1;
          p = p * v + C0;
          acc = acc + scb * (p * x);
        }
      }
      ((float2*)sh_pa)[btp * 9 + bhc] = make_float2((float)acc.x, (float)acc.y);
    }
    __syncthreads();

    // ---- C: p (unnormalized) + local S ----
    if (tid < 128) {
      float e0 = 0.f, e1 = 0.f;
#pragma unroll
      for (int k = 0; k < 8; ++k) {
        float2 v = ((const float2*)sh_pa)[tid * 9 + k];
        e0 += v.x;
        e1 += v.y;
      }
      float p0 = exp2f(e0 * 1.44269504f);
      float p1 = exp2f(e1 * 1.44269504f);
      sh_alpha2[tid] = packh2(p0, p1);
      float s = wave_sum64(p0 + p1);
      if (lane == 63) sh_red[wid] = s;
    }
    __syncthreads();
    if (tid == 0) S_cur[g * 4 + j] = sh_red[0] + sh_red[1];

    // ---- D': software-pipelined over 4 chunks of 8 t-pairs ----
    if (tid < 768) {
      float a0 = 0.f, a1 = 0.f, a2 = 0.f, a3 = 0.f;
#pragma unroll
      for (int c = 0; c < 4; ++c) {
        uint4 nx[8];
        if (c < 3) {
#pragma unroll
          for (int i = 0; i < 8; ++i) nx[i] = frbase[(long)((c + 1) * 8 + i) * 192];
        }
#pragma unroll
        for (int i = 0; i < 8; ++i) {
          v2h al = u2v(sh_alpha2[dsub * 32 + c * 8 + i]);
          a0 = f_dot2(al, u2v(cur[i].x), a0);
          a1 = f_dot2(al, u2v(cur[i].y), a1);
          a2 = f_dot2(al, u2v(cur[i].z), a2);
          a3 = f_dot2(al, u2v(cur[i].w), a3);
        }
        if (c < 3) {
#pragma unroll
          for (int i = 0; i < 8; ++i) cur[i] = nx[i];
        }
      }
      *(float4*)&sh_pa[dsub * GDIM + dcg * 4] = make_float4(a0, a1, a2, a3);
    }
    __syncthreads();
    // reduce the 4 sub-chunks -> global exchange buffer
    if (tid < 768) {
      float v = sh_pa[tid] + sh_pa[GDIM + tid] + sh_pa[2 * GDIM + tid] + sh_pa[3 * GDIM + tid];
      gxp_cur[((long)g * 4 + j) * GDIM + tid] = v;
    }

    // ---- single barrier ----
    __syncthreads();
    if (tid == 0) {
      __hip_atomic_fetch_add(&bar1[g], 1, __ATOMIC_ACQ_REL, __HIP_MEMORY_SCOPE_AGENT);
      const int tgt4 = 4 * (step + 1);
      while (__hip_atomic_load(&bar1[g], __ATOMIC_RELAXED, __HIP_MEMORY_SCOPE_AGENT) < tgt4)
        __builtin_amdgcn_s_sleep(2);
      (void)__hip_atomic_load(&bar1[g], __ATOMIC_ACQUIRE, __HIP_MEMORY_SCOPE_AGENT);
    }
    __syncthreads();

    // ---- G: gates -> h_new (replicated, bit-identical) ----
    if (tid < 256) {
      float D = S_cur[g * 4] + S_cur[g * 4 + 1] + S_cur[g * 4 + 2] + S_cur[g * 4 + 3];
      float rs = 1.0f / D;
      const float* eb = embb + (long)tgt * GDIM;
      float gr = 0.f, gz = 0.f, gn = 0.f;
#pragma unroll
      for (int jj = 0; jj < 4; ++jj) {
        const float* gp = gxp_cur + ((long)g * 4 + jj) * GDIM;
        gr += gp[tid];
        gz += gp[tid + 256];
        gn += gp[tid + 512];
      }
      gr = gr * rs + eb[tid];
      gz = gz * rs + eb[tid + 256];
      gn = gn * rs + eb[tid + 512];
      const float* gh = ghx_cur + (long)g * GDIM;
      float hr = gh[tid], hz = gh[tid + 256], hn = gh[tid + 512];
      float r = 1.f / (1.f + __expf(-(gr + hr)));
      float z = 1.f / (1.f + __expf(-(gz + hz)));
      float n = tanhf(gn + r * hn);
      sh_hidden[tid] = (1.f - z) * n + z * sh_hidden[tid];
    }
    __syncthreads();

    // ---- H: repack h2; rotating leader writes outputs ----
    if (tid < 128) sh_h2[tid] = packh2(sh_hidden[2 * tid], sh_hidden[2 * tid + 1]);
    if (j == (step & 3)) {
      float hv[4];
      if (tid < 64) {
#pragma unroll
        for (int k = 0; k < 4; ++k) hv[k] = sh_hidden[lane + 64 * k];
      }
      if (tid < 34) {
        float a = comb_b[tid];
#pragma unroll
        for (int k = 0; k < 4; ++k) {
          for (int l = 0; l < 64; ++l) {
            float h = __builtin_bit_cast(
                float, __builtin_amdgcn_readlane(__builtin_bit_cast(int, hv[k]), l));
            a += h * comb_w[(64 * k + l) * 34 + tid];
          }
        }
        long so;
        float vv;
        if (tid < 30) {
          so = ((long)g * steps + step) * 30 + tid;
          vv = a;
        } else {
          so = (long)BB * steps * 30 + ((long)g * steps + step) * 4 + (tid - 30);
          vv = 1.f / (1.f + __expf(-a));
        }
        if (isb)
          ((__hip_bfloat16*)out)[so] = __float2bfloat16(vv);
        else
          ((float*)out)[so] = vv;
      }
    }
    __syncthreads();
  }
}

// ---------------- host: tanh poly fit ----------------
static void fit_tanh(float cf[7]) {
  double A[7][7] = {{0}}, r[7] = {0};
  const int N = 1024;
  for (int i = 1; i <= N; ++i) {
    double x = 3.9 * i / N;
    double v = (x * x) / 16.0;
    double t = tanh(x);
    double phi[7];
    double pw = x;
    for (int jj = 0; jj < 7; ++jj) {
      phi[jj] = pw;
      pw *= v;
    }
    for (int jj = 0; jj < 7; ++jj) {
      r[jj] += phi[jj] * t;
      for (int k = 0; k < 7; ++k) A[jj][k] += phi[jj] * phi[k];
    }
  }
  for (int col = 0; col < 7; ++col) {
    int piv = col;
    for (int rr = col + 1; rr < 7; ++rr)
      if (fabs(A[rr][col]) > fabs(A[piv][col])) piv = rr;
    if (piv != col) {
      for (int k = 0; k < 7; ++k) {
        double tmp = A[col][k];
        A[col][k] = A[piv][k];
        A[piv][k] = tmp;
      }
      double tb = r[col];
      r[col] = r[piv];
      r[piv] = tb;
    }
    double d = A[col][col];
    for (int rr = col + 1; rr < 7; ++rr) {
      double f = A[rr][col] / d;
      for (int k = col; k < 7; ++k) A[rr][k] -= f * A[col][k];
      r[rr] -= f * r[col];
    }
  }
  double c[7];
  for (int col = 6; col >= 0; --col) {
    double ss = r[col];
    for (int k = col + 1; k < 7; ++k) ss -= A[col][k] * c[k];
    c[col] = ss / A[col][col];
  }
  for (int jj = 0; jj < 7; ++jj) cf[jj] = (float)c[jj];
}

extern "C" void kernel_launch(void* const* d_in, const int* in_sizes, int n_in, void* d_out,
                              int out_size, void* d_ws, size_t ws_size, hipStream_t stream) {
  (void)n_in;
  (void)out_size;
  (void)ws_size;
  const void* fea = d_in[0];
  const int* targets = (const int*)d_in[1];
  const void* i2h_w = d_in[2];
  const void* h2h_w = d_in[3];
  const void* h2h_b = d_in[4];
  const void* score_w = d_in[5];
  const void* gru_w_ih = d_in[6];
  const void* gru_w_hh = d_in[7];
  const void* gru_b_ih = d_in[8];
  const void* gru_b_hh = d_in[9];
  const void* sg1_w = d_in[10];
  const void* sg1_b = d_in[11];
  const void* sg2_w = d_in[12];
  const void* sg2_b = d_in[13];
  const void* lg1_w = d_in[14];
  const void* lg1_b = d_in[15];
  const void* lg2_w = d_in[16];
  const void* lg2_b = d_in[17];
  const int steps = in_sizes[1] / BB;  // 501

  char* p = (char*)d_ws;
  auto alloc = [&](size_t bytes) {
    char* r = p;
    p += (bytes + 255) & ~(size_t)255;
    return r;
  };
  unsigned* pp = (unsigned*)alloc((size_t)BB * 512 * 256 * 4);     // 33.5 MB (t-pair-major proj)
  unsigned* fw2 = (unsigned*)alloc((size_t)BB * 512 * GDIM * 4);   // 100.7 MB
  unsigned* wc2 = (unsigned*)alloc((size_t)256 * 1024 * 4);        // 1 MB
  unsigned* w4t = (unsigned*)alloc((size_t)128 * 1024 * 4);        // 0.5 MB (transposed)
  float* bias4 = (float*)alloc(1024 * 4);
  float* embb = (float*)alloc((size_t)NEMB * GDIM * 4);
  float* scoref = (float*)alloc(256 * 4);
  float* combw = (float*)alloc(256 * 34 * 4);
  float* combb = (float*)alloc(64 * 4);
  int* flag = (int*)alloc(256);
  int* bars = (int*)alloc(4096);
  float* Sx = (float*)alloc((size_t)2 * 64 * 4 * 4);
  float* ghxx = (float*)alloc((size_t)2 * 64 * GDIM * 4);
  float* gxpx = (float*)alloc((size_t)2 * 64 * 4 * GDIM * 4);
  int* bar1 = bars;

  TanhC tc;
  fit_tanh(tc.c);

  hipMemsetAsync(bars, 0, 4096, stream);
  k_sniff<<<1, 256, 0, stream>>>(fea, flag);
  k_wc<<<1024, 256, 0, stream>>>(i2h_w, gru_w_ih, wc2, flag);
  k_w4t<<<512, 256, 0, stream>>>(h2h_w, gru_w_hh, w4t, flag);
  k_bias4<<<4, 256, 0, stream>>>(h2h_b, gru_b_hh, bias4, flag);
  k_embb<<<90, 256, 0, stream>>>(gru_w_ih, gru_b_ih, embb, flag);
  k_cvt_f<<<1, 256, 0, stream>>>(score_w, scoref, 256, flag);
  k_comb<<<1, 256, 0, stream>>>(sg1_w, sg1_b, sg2_w, sg2_b, lg1_w, lg1_b, lg2_w, lg2_b, combw,
                                combb, flag);
  k_gemm<<<4096, 256, 0, stream>>>(fea, wc2, pp, fw2, flag);

  k_main_c3<<<256, 1024, 0, stream>>>(pp, fw2, targets, w4t, bias4, embb, scoref, combw, combb,
                                      d_out, flag, steps, tc, bar1, Sx, ghxx, gxpx);
}

// Round 8
// 47803.827 us; speedup vs baseline: 1.1515x; 1.1515x over previous
//
#include <hip/hip_runtime.h>
#include <hip/hip_bf16.h>
#include <hip/hip_fp16.h>
#include <math.h>

#define BB 64
#define CDIM 512
#define TT 1024
#define HID 256
#define NEMB 30
#define GDIM 768

typedef _Float16 v2h __attribute__((ext_vector_type(2)));

struct TanhC { float c[7]; };

__device__ inline float f_dot2(v2h a, v2h b, float c) {
  return __builtin_amdgcn_fdot2(a, b, c, false);
}
__device__ inline v2h u2v(unsigned u) { return __builtin_bit_cast(v2h, u); }
__device__ inline unsigned v2u(v2h h) { return __builtin_bit_cast(unsigned, h); }
__device__ inline unsigned packh2(float a, float b) {
  v2h t = {(_Float16)a, (_Float16)b};
  return v2u(t);
}
__device__ inline v2h v2splat(float f) {
  _Float16 h = (_Float16)f;
  v2h r = {h, h};
  return r;
}

// async global->LDS 16B: lds dest = uniform base + lane*16 (HW); g is per-lane
__device__ inline void cp16_lds(const unsigned* g, unsigned* ldsbase, int lane) {
#if __has_builtin(__builtin_amdgcn_global_load_lds)
  (void)lane;
  __builtin_amdgcn_global_load_lds((const __attribute__((address_space(1))) unsigned*)g,
                                   (__attribute__((address_space(3))) unsigned*)ldsbase, 16, 0, 0);
#else
  *(uint4*)(ldsbase + lane * 4) = *(const uint4*)g;
#endif
}

// input loader: isb=1 -> bf16, else f32
__device__ inline float ldin(const void* p, long i, int isb) {
  if (isb) {
    unsigned u = ((const unsigned short*)p)[i];
    return __uint_as_float(u << 16);
  }
  return ((const float*)p)[i];
}

template <int CTRL, int RM, int BM, bool BC>
__device__ inline float dpp_add(float v) {
  int m = __builtin_amdgcn_update_dpp(0, __builtin_bit_cast(int, v), CTRL, RM, BM, BC);
  return v + __builtin_bit_cast(float, m);
}
__device__ inline float wave_sum64(float v) {
  v = dpp_add<0x111, 0xf, 0xf, true>(v);
  v = dpp_add<0x112, 0xf, 0xf, true>(v);
  v = dpp_add<0x114, 0xf, 0xe, false>(v);
  v = dpp_add<0x118, 0xf, 0xc, false>(v);
  v = dpp_add<0x142, 0xa, 0xf, false>(v);
  v = dpp_add<0x143, 0xc, 0xf, false>(v);
  return v;
}

// ---------------- dtype sniffer ----------------
__global__ void k_sniff(const void* fea, int* flag) {
  __shared__ int s[256];
  int tid = threadIdx.x;
  const unsigned short* u16 = (const unsigned short*)fea;
  int cnt = 0;
  for (int i = tid; i < 2048; i += 256) {
    unsigned u = u16[2 * i];
    float v = __uint_as_float(u << 16);
    float a = fabsf(v);
    if (a > 1e-6f && a < 16.0f) cnt++;
  }
  s[tid] = cnt;
  __syncthreads();
  for (int off = 128; off > 0; off >>= 1) {
    if (tid < off) s[tid] += s[tid + off];
    __syncthreads();
  }
  if (tid == 0) flag[0] = (s[0] > 1024) ? 1 : 0;
}

__global__ void k_cvt_f(const void* src, float* dst, long n, const int* flag) {
  int isb = flag[0];
  long i = (long)blockIdx.x * blockDim.x + threadIdx.x;
  long stride = (long)gridDim.x * blockDim.x;
  for (; i < n; i += stride) dst[i] = ldin(src, i, isb);
}

// Wc2[cp][col]: pair-rows of [i2h (cols 0-255) | Wih[:512] (cols 256-1023)], half2 bits
__global__ void k_wc(const void* i2h, const void* wih, unsigned* wc2, const int* flag) {
  int isb = flag[0];
  int idx = blockIdx.x * 256 + threadIdx.x;  // 1024 blocks
  int cp = idx >> 10, col = idx & 1023;
  float a, b;
  if (col < 256) {
    a = ldin(i2h, (long)(2 * cp) * 256 + col, isb);
    b = ldin(i2h, (long)(2 * cp + 1) * 256 + col, isb);
  } else {
    int j = col - 256;
    a = ldin(wih, (long)(2 * cp) * GDIM + j, isb);
    b = ldin(wih, (long)(2 * cp + 1) * GDIM + j, isb);
  }
  wc2[idx] = packh2(a, b);
}

// w4t[col][l]: TRANSPOSED pair-rows of [h2h (cols 0-255) | whh (cols 256-1023)]
__global__ void k_w4t(const void* h2hw, const void* whhw, unsigned* w4t, const int* flag) {
  int isb = flag[0];
  int idx = blockIdx.x * 256 + threadIdx.x;  // 512 blocks -> 131072
  int col = idx >> 7, l = idx & 127;
  float a, b2;
  if (col < 256) {
    a = ldin(h2hw, (long)(2 * l) * 256 + col, isb);
    b2 = ldin(h2hw, (long)(2 * l + 1) * 256 + col, isb);
  } else {
    int j = col - 256;
    a = ldin(whhw, (long)(2 * l) * GDIM + j, isb);
    b2 = ldin(whhw, (long)(2 * l + 1) * GDIM + j, isb);
  }
  w4t[idx] = packh2(a, b2);
}

__global__ void k_bias4(const void* h2hb, const void* bhh, float* bias4, const int* flag) {
  int isb = flag[0];
  int col = blockIdx.x * 256 + threadIdx.x;  // 4 blocks
  bias4[col] = (col < 256) ? ldin(h2hb, col, isb) : ldin(bhh, col - 256, isb);
}

// embb[e][col] = Wih[512+e][col] + b_ih[col]
__global__ void k_embb(const void* wih, const void* bih, float* embb, const int* flag) {
  int isb = flag[0];
  int idx = blockIdx.x * 256 + threadIdx.x;  // 90 blocks
  if (idx >= NEMB * GDIM) return;
  int e = idx / GDIM, col = idx % GDIM;
  embb[idx] = ldin(wih, (long)(512 + e) * GDIM + col, isb) + ldin(bih, col, isb);
}

// combined output head
__global__ void k_comb(const void* sg1w, const void* sg1b, const void* sg2w, const void* sg2b,
                       const void* lg1w, const void* lg1b, const void* lg2w, const void* lg2b,
                       float* comb_w, float* comb_b, const int* flag) {
  int isb = flag[0];
  int tid = threadIdx.x;
  float acc[34];
#pragma unroll
  for (int o = 0; o < 34; ++o) acc[o] = 0.f;
  for (int m = 0; m < HID; ++m) {
    float s1 = ldin(sg1w, (long)tid * HID + m, isb);
    float l1 = ldin(lg1w, (long)tid * HID + m, isb);
#pragma unroll
    for (int o = 0; o < 30; ++o) acc[o] += s1 * ldin(sg2w, (long)m * NEMB + o, isb);
#pragma unroll
    for (int o = 0; o < 4; ++o) acc[30 + o] += l1 * ldin(lg2w, (long)m * 4 + o, isb);
  }
  for (int o = 0; o < 34; ++o) comb_w[tid * 34 + o] = acc[o];
  if (tid < 34) {
    float a = 0.f;
    if (tid < 30) {
      for (int m = 0; m < HID; ++m) a += ldin(sg1b, m, isb) * ldin(sg2w, (long)m * NEMB + tid, isb);
      a += ldin(sg2b, tid, isb);
    } else {
      int o = tid - 30;
      for (int m = 0; m < HID; ++m) a += ldin(lg1b, m, isb) * ldin(lg2w, (long)m * 4 + o, isb);
      a += ldin(lg2b, o, isb);
    }
    comb_b[tid] = a;
  }
}

// ---------------- tiled GEMM: C[b][t][col] = fea[b][:,t] . Wc[:,col] ----------------
__global__ __launch_bounds__(256) void k_gemm(const void* fea, const unsigned* wc2,
                                              unsigned* pp, unsigned* fw2, const int* flag) {
  const int isb = flag[0];
  const int blk = blockIdx.x;
  const int b = blk >> 6;
  const int tt = (blk >> 3) & 7;
  const int cc = blk & 7;
  const int t0 = tt * 128, c0 = cc * 128;
  __shared__ __align__(16) unsigned At[32][136];
  __shared__ __align__(16) unsigned Wt[32][136];
  const int tid = threadIdx.x;
  const int cp_l = tid >> 3, sg = tid & 7;
  const int tm = tid & 15, tn = tid >> 4;
  float acc[8][8];
#pragma unroll
  for (int i = 0; i < 8; ++i)
#pragma unroll
    for (int jj = 0; jj < 8; ++jj) acc[i][jj] = 0.f;

  for (int kt = 0; kt < 8; ++kt) {
    const int crow = (kt * 32 + cp_l) * 2;
    if (isb) {
      const unsigned short* f0p =
          (const unsigned short*)fea + ((long)b * CDIM + crow) * TT + t0 + sg * 16;
      const unsigned short* f1p = f0p + TT;
#pragma unroll
      for (int q = 0; q < 2; ++q) {
        ushort4 u0a = ((const ushort4*)f0p)[2 * q];
        ushort4 u0b = ((const ushort4*)f0p)[2 * q + 1];
        ushort4 u1a = ((const ushort4*)f1p)[2 * q];
        ushort4 u1b = ((const ushort4*)f1p)[2 * q + 1];
        unsigned short a0[8] = {u0a.x, u0a.y, u0a.z, u0a.w, u0b.x, u0b.y, u0b.z, u0b.w};
        unsigned short a1[8] = {u1a.x, u1a.y, u1a.z, u1a.w, u1b.x, u1b.y, u1b.z, u1b.w};
#pragma unroll
        for (int e = 0; e < 8; ++e) {
          float f0 = __uint_as_float(((unsigned)a0[e]) << 16);
          float f1 = __uint_as_float(((unsigned)a1[e]) << 16);
          At[cp_l][sg * 16 + q * 8 + e] = packh2(f0, f1);
        }
      }
    } else {
      const float* f0p = (const float*)fea + ((long)b * CDIM + crow) * TT + t0 + sg * 16;
      const float* f1p = f0p + TT;
#pragma unroll
      for (int q = 0; q < 4; ++q) {
        float4 v0 = ((const float4*)f0p)[q];
        float4 v1 = ((const float4*)f1p)[q];
        At[cp_l][sg * 16 + q * 4 + 0] = packh2(v0.x, v1.x);
        At[cp_l][sg * 16 + q * 4 + 1] = packh2(v0.y, v1.y);
        At[cp_l][sg * 16 + q * 4 + 2] = packh2(v0.z, v1.z);
        At[cp_l][sg * 16 + q * 4 + 3] = packh2(v0.w, v1.w);
      }
    }
    {
      const uint4* wp = (const uint4*)(wc2 + (long)(kt * 32 + cp_l) * 1024 + c0 + sg * 16);
#pragma unroll
      for (int q = 0; q < 4; ++q) {
        uint4 w = wp[q];
        Wt[cp_l][sg * 16 + q * 4 + 0] = w.x;
        Wt[cp_l][sg * 16 + q * 4 + 1] = w.y;
        Wt[cp_l][sg * 16 + q * 4 + 2] = w.z;
        Wt[cp_l][sg * 16 + q * 4 + 3] = w.w;
      }
    }
    __syncthreads();
    for (int cp = 0; cp < 32; ++cp) {
      uint4 aq0 = *(const uint4*)&At[cp][tm * 4];
      uint4 aq1 = *(const uint4*)&At[cp][64 + tm * 4];
      uint4 bq0 = *(const uint4*)&Wt[cp][tn * 4];
      uint4 bq1 = *(const uint4*)&Wt[cp][64 + tn * 4];
      unsigned av[8] = {aq0.x, aq0.y, aq0.z, aq0.w, aq1.x, aq1.y, aq1.z, aq1.w};
      unsigned bv[8] = {bq0.x, bq0.y, bq0.z, bq0.w, bq1.x, bq1.y, bq1.z, bq1.w};
#pragma unroll
      for (int ti = 0; ti < 8; ++ti)
#pragma unroll
        for (int ci = 0; ci < 8; ++ci)
          acc[ti][ci] = f_dot2(u2v(av[ti]), u2v(bv[ci]), acc[ti][ci]);
    }
    __syncthreads();
  }

#pragma unroll
  for (int q = 0; q < 2; ++q) {
    const int tq = t0 + q * 64 + tm * 4;
#pragma unroll
    for (int pr = 0; pr < 2; ++pr) {
      const int tp = (tq >> 1) + pr;
      const int r0 = q * 4 + 2 * pr, r1 = r0 + 1;
      unsigned* row;
      if (cc < 2)
        row = pp + ((long)b * 512 + tp) * 256 + c0 + tn * 4;
      else
        row = fw2 + ((long)b * 512 + tp) * GDIM + (c0 - 256) + tn * 4;
      uint4 pa = {packh2(acc[r0][0], acc[r1][0]), packh2(acc[r0][1], acc[r1][1]),
                  packh2(acc[r0][2], acc[r1][2]), packh2(acc[r0][3], acc[r1][3])};
      uint4 pb = {packh2(acc[r0][4], acc[r1][4]), packh2(acc[r0][5], acc[r1][5]),
                  packh2(acc[r0][6], acc[r1][6]), packh2(acc[r0][7], acc[r1][7])};
      *(uint4*)row = pa;
      *(uint4*)(row + 64) = pb;
    }
  }
}

// ---------------- cooperative main v4: 256 blocks (4/batch) x 1024 threads ----------------
// D' uses per-wave global_load_lds triple-buffer pipeline (no barriers inside D').
__global__ __launch_bounds__(1024, 4) void k_main_c4(
    const unsigned* pp, const unsigned* fw2, const int* targets, const unsigned* w4t,
    const float* bias4, const float* embb, const float* scoref, const float* comb_w,
    const float* comb_b, void* out, const int* flag, int steps, TanhC tc, int* bar1, float* Sx,
    float* ghxx, float* gxpx) {
  const int tid = threadIdx.x;
  const int g = blockIdx.x & 63;  // batch
  const int j = blockIdx.x >> 6;  // 0..3 within group
  const int lane = tid & 63, wid = tid >> 6;
  const int isb = flag[0];

  __shared__ __align__(16) float sh_pa[2304];          // A partials (1792) / B partials (2304)
  __shared__ __align__(16) unsigned sh_fw[12][3][256]; // per-wave D' staging, 36 KB
  __shared__ unsigned sh_phsc[264];                    // swizzled (ph,score)
  __shared__ unsigned sh_alpha2[128];                  // unnormalized p pairs (f16)
  __shared__ float sh_hidden[HID];
  __shared__ unsigned sh_h2[128];
  __shared__ float sh_red[4];

  float my_sc = (tid < HID) ? scoref[tid] : 0.f;
  if (tid < HID) sh_hidden[tid] = 0.f;
  if (tid < 128) sh_h2[tid] = 0u;
  __syncthreads();

  const v2h C0 = v2splat(tc.c[0]), C1 = v2splat(tc.c[1]), C2 = v2splat(tc.c[2]),
            C3 = v2splat(tc.c[3]), C4 = v2splat(tc.c[4]), C5 = v2splat(tc.c[5]),
            C6 = v2splat(tc.c[6]);
  const v2h CLO = v2splat(-3.9f), CHI = v2splat(3.9f);
  const v2h VS = v2splat(0.0625f);

  const unsigned* ppbase = pp + ((long)g * 512 + j * 128) * 256;
  const unsigned* fwbase = fw2 + ((long)g * 512 + j * 128) * GDIM;

  // D' DMA mapping: wave wid (<12) owns col stripe wid*64; chunk=4 t-pair rows.
  // lane fetches row ck*4 + (lane>>4), cols wid*64 + (lane&15)*4 .. +4
  const long dma_lane_off = (long)(lane >> 4) * GDIM + wid * 64 + (lane & 15) * 4;

  // B mapping
  const int btp = tid >> 3, bhc = tid & 7;
  const uint4* prow = (const uint4*)(ppbase + (long)btp * 256) + bhc * 8;

  // A mapping (w4t contiguous in l)
  const int achunk = tid >> 8, acol = tid & 255;
  const uint4* awp = (const uint4*)(w4t + (long)acol * 128 + achunk * 32);
  const int gch = (tid < 768) ? tid / 192 : 0;
  const int gcl = (tid < 768) ? tid % 192 : 0;
  const int gcol = 256 + j * 192 + gcl;
  const uint4* gwp = (const uint4*)(w4t + (long)gcol * 128 + gch * 32);

  for (int step = 0; step < steps; ++step) {
    const int tgt = targets[g * steps + step];
    const int par = step & 1;
    float* S_cur = Sx + par * 256;
    float* ghx_cur = ghxx + (long)par * 64 * GDIM;
    float* gxp_cur = gxpx + (long)par * 64 * 4 * GDIM;

    // ---- prologue: issue D' chunks 0..2 via LDS-DMA (hidden under A/B/C) ----
    if (wid < 12) {
#pragma unroll
      for (int ck = 0; ck < 3; ++ck)
        cp16_lds(fwbase + (long)ck * 4 * GDIM + dma_lane_off, &sh_fw[wid][ck][0], lane);
    }

    // ---- A: ph (replicated) + gh slice j ; batched contiguous w4t loads ----
    {
      float a = 0.f;
#pragma unroll
      for (int half = 0; half < 2; ++half) {
#pragma unroll
        for (int q = 0; q < 4; ++q) {
          uint4 w = awp[half * 4 + q];
          int l0 = achunk * 32 + half * 16 + q * 4;
          a = f_dot2(u2v(sh_h2[l0 + 0]), u2v(w.x), a);
          a = f_dot2(u2v(sh_h2[l0 + 1]), u2v(w.y), a);
          a = f_dot2(u2v(sh_h2[l0 + 2]), u2v(w.z), a);
          a = f_dot2(u2v(sh_h2[l0 + 3]), u2v(w.w), a);
        }
      }
      sh_pa[achunk * 256 + acol] = a;
    }
    if (tid < 768) {
      float a = 0.f;
#pragma unroll
      for (int half = 0; half < 2; ++half) {
#pragma unroll
        for (int q = 0; q < 4; ++q) {
          uint4 w = gwp[half * 4 + q];
          int l0 = gch * 32 + half * 16 + q * 4;
          a = f_dot2(u2v(sh_h2[l0 + 0]), u2v(w.x), a);
          a = f_dot2(u2v(sh_h2[l0 + 1]), u2v(w.y), a);
          a = f_dot2(u2v(sh_h2[l0 + 2]), u2v(w.z), a);
          a = f_dot2(u2v(sh_h2[l0 + 3]), u2v(w.w), a);
        }
      }
      sh_pa[1024 + gch * 192 + gcl] = a;
    }
    __syncthreads();
    if (tid < 256) {
      float ph = sh_pa[tid] + sh_pa[256 + tid] + sh_pa[512 + tid] + sh_pa[768 + tid] + bias4[tid];
      sh_phsc[(tid >> 5) * 33 + (tid & 31)] = packh2(ph, my_sc);
    } else if (tid < 448) {
      int cl = tid - 256;
      float gv = sh_pa[1024 + cl] + sh_pa[1024 + 192 + cl] + sh_pa[1024 + 384 + cl] +
                 sh_pa[1024 + 576 + cl] + bias4[256 + j * 192 + cl];
      ghx_cur[(long)g * GDIM + j * 192 + cl] = gv;
    }
    __syncthreads();

    // ---- B: e partials; thread = (t-pair btp, h-chunk bhc of 32) ----
    {
      v2h acc = v2splat(0.f);
#pragma unroll
      for (int q = 0; q < 8; ++q) {
        uint4 w = prow[q];
        unsigned we[4] = {w.x, w.y, w.z, w.w};
#pragma unroll
        for (int e = 0; e < 4; ++e) {
          int hl = q * 4 + e;
          v2h ps = u2v(sh_phsc[bhc * 33 + hl]);
          v2h phb = {ps.x, ps.x};
          v2h scb = {ps.y, ps.y};
          v2h x = u2v(we[e]) + phb;
          x = __builtin_elementwise_max(x, CLO);
          x = __builtin_elementwise_min(x, CHI);
          v2h v = x * x * VS;
          v2h p = C6;
          p = p * v + C5;
          p = p * v + C4;
          p = p * v + C3;
          p = p * v + C2;
          p = p * v + C1;
          p = p * v + C0;
          acc = acc + scb * (p * x);
        }
      }
      ((float2*)sh_pa)[btp * 9 + bhc] = make_float2((float)acc.x, (float)acc.y);
    }
    __syncthreads();

    // ---- C: p (unnormalized) + local S ----
    if (tid < 128) {
      float e0 = 0.f, e1 = 0.f;
#pragma unroll
      for (int k = 0; k < 8; ++k) {
        float2 v = ((const float2*)sh_pa)[tid * 9 + k];
        e0 += v.x;
        e1 += v.y;
      }
      float p0 = exp2f(e0 * 1.44269504f);
      float p1 = exp2f(e1 * 1.44269504f);
      sh_alpha2[tid] = packh2(p0, p1);
      float s = wave_sum64(p0 + p1);
      if (lane == 63) sh_red[wid] = s;
    }
    __syncthreads();
    if (tid == 0) S_cur[g * 4 + j] = sh_red[0] + sh_red[1];

    // ---- D': per-wave DMA pipeline, 32 chunks of 4 t-pairs, triple buffer, no barriers ----
    if (wid < 12) {
      float dacc = 0.f;
#pragma unroll
      for (int ck = 0; ck < 32; ++ck) {
        if (ck < 30)
          asm volatile("s_waitcnt vmcnt(2)" ::: "memory");
        else if (ck == 30)
          asm volatile("s_waitcnt vmcnt(1)" ::: "memory");
        else
          asm volatile("s_waitcnt vmcnt(0)" ::: "memory");
#pragma unroll
        for (int r = 0; r < 4; ++r) {
          unsigned f = sh_fw[wid][ck % 3][r * 64 + lane];
          dacc = f_dot2(u2v(sh_alpha2[ck * 4 + r]), u2v(f), dacc);
        }
        if (ck + 3 < 32) {
          asm volatile("s_waitcnt lgkmcnt(0)" ::: "memory");
          cp16_lds(fwbase + (long)(ck + 3) * 4 * GDIM + dma_lane_off, &sh_fw[wid][ck % 3][0],
                   lane);
        }
      }
      gxp_cur[((long)g * 4 + j) * GDIM + wid * 64 + lane] = dacc;
    }

    // ---- single group barrier ----
    __syncthreads();
    if (tid == 0) {
      __hip_atomic_fetch_add(&bar1[g], 1, __ATOMIC_ACQ_REL, __HIP_MEMORY_SCOPE_AGENT);
      const int tgt4 = 4 * (step + 1);
      while (__hip_atomic_load(&bar1[g], __ATOMIC_RELAXED, __HIP_MEMORY_SCOPE_AGENT) < tgt4)
        __builtin_amdgcn_s_sleep(2);
      (void)__hip_atomic_load(&bar1[g], __ATOMIC_ACQUIRE, __HIP_MEMORY_SCOPE_AGENT);
    }
    __syncthreads();

    // ---- G: gates -> h_new (replicated, bit-identical) ----
    if (tid < 256) {
      float D = S_cur[g * 4] + S_cur[g * 4 + 1] + S_cur[g * 4 + 2] + S_cur[g * 4 + 3];
      float rs = 1.0f / D;
      const float* eb = embb + (long)tgt * GDIM;
      float gr = 0.f, gz = 0.f, gn = 0.f;
#pragma unroll
      for (int jj = 0; jj < 4; ++jj) {
        const float* gp = gxp_cur + ((long)g * 4 + jj) * GDIM;
        gr += gp[tid];
        gz += gp[tid + 256];
        gn += gp[tid + 512];
      }
      gr = gr * rs + eb[tid];
      gz = gz * rs + eb[tid + 256];
      gn = gn * rs + eb[tid + 512];
      const float* gh = ghx_cur + (long)g * GDIM;
      float hr = gh[tid], hz = gh[tid + 256], hn = gh[tid + 512];
      float r = 1.f / (1.f + __expf(-(gr + hr)));
      float z = 1.f / (1.f + __expf(-(gz + hz)));
      float n = tanhf(gn + r * hn);
      sh_hidden[tid] = (1.f - z) * n + z * sh_hidden[tid];
    }
    __syncthreads();

    // ---- H: repack h2; rotating leader writes outputs ----
    if (tid < 128) sh_h2[tid] = packh2(sh_hidden[2 * tid], sh_hidden[2 * tid + 1]);
    if (j == (step & 3)) {
      float hv[4];
      if (tid < 64) {
#pragma unroll
        for (int k = 0; k < 4; ++k) hv[k] = sh_hidden[lane + 64 * k];
      }
      if (tid < 34) {
        float a = comb_b[tid];
#pragma unroll
        for (int k = 0; k < 4; ++k) {
          for (int l = 0; l < 64; ++l) {
            float h = __builtin_bit_cast(
                float, __builtin_amdgcn_readlane(__builtin_bit_cast(int, hv[k]), l));
            a += h * comb_w[(64 * k + l) * 34 + tid];
          }
        }
        long so;
        float vv;
        if (tid < 30) {
          so = ((long)g * steps + step) * 30 + tid;
          vv = a;
        } else {
          so = (long)BB * steps * 30 + ((long)g * steps + step) * 4 + (tid - 30);
          vv = 1.f / (1.f + __expf(-a));
        }
        if (isb)
          ((__hip_bfloat16*)out)[so] = __float2bfloat16(vv);
        else
          ((float*)out)[so] = vv;
      }
    }
    __syncthreads();
  }
}

// ---------------- host: tanh poly fit ----------------
static void fit_tanh(float cf[7]) {
  double A[7][7] = {{0}}, r[7] = {0};
  const int N = 1024;
  for (int i = 1; i <= N; ++i) {
    double x = 3.9 * i / N;
    double v = (x * x) / 16.0;
    double t = tanh(x);
    double phi[7];
    double pw = x;
    for (int jj = 0; jj < 7; ++jj) {
      phi[jj] = pw;
      pw *= v;
    }
    for (int jj = 0; jj < 7; ++jj) {
      r[jj] += phi[jj] * t;
      for (int k = 0; k < 7; ++k) A[jj][k] += phi[jj] * phi[k];
    }
  }
  for (int col = 0; col < 7; ++col) {
    int piv = col;
    for (int rr = col + 1; rr < 7; ++rr)
      if (fabs(A[rr][col]) > fabs(A[piv][col])) piv = rr;
    if (piv != col) {
      for (int k = 0; k < 7; ++k) {
        double tmp = A[col][k];
        A[col][k] = A[piv][k];
        A[piv][k] = tmp;
      }
      double tb = r[col];
      r[col] = r[piv];
      r[piv] = tb;
    }
    double d = A[col][col];
    for (int rr = col + 1; rr < 7; ++rr) {
      double f = A[rr][col] / d;
      for (int k = col; k < 7; ++k) A[rr][k] -= f * A[col][k];
      r[rr] -= f * r[col];
    }
  }
  double c[7];
  for (int col = 6; col >= 0; --col) {
    double ss = r[col];
    for (int k = col + 1; k < 7; ++k) ss -= A[col][k] * c[k];
    c[col] = ss / A[col][col];
  }
  for (int jj = 0; jj < 7; ++jj) cf[jj] = (float)c[jj];
}

extern "C" void kernel_launch(void* const* d_in, const int* in_sizes, int n_in, void* d_out,
                              int out_size, void* d_ws, size_t ws_size, hipStream_t stream) {
  (void)n_in;
  (void)out_size;
  (void)ws_size;
  const void* fea = d_in[0];
  const int* targets = (const int*)d_in[1];
  const void* i2h_w = d_in[2];
  const void* h2h_w = d_in[3];
  const void* h2h_b = d_in[4];
  const void* score_w = d_in[5];
  const void* gru_w_ih = d_in[6];
  const void* gru_w_hh = d_in[7];
  const void* gru_b_ih = d_in[8];
  const void* gru_b_hh = d_in[9];
  const void* sg1_w = d_in[10];
  const void* sg1_b = d_in[11];
  const void* sg2_w = d_in[12];
  const void* sg2_b = d_in[13];
  const void* lg1_w = d_in[14];
  const void* lg1_b = d_in[15];
  const void* lg2_w = d_in[16];
  const void* lg2_b = d_in[17];
  const int steps = in_sizes[1] / BB;  // 501

  char* p = (char*)d_ws;
  auto alloc = [&](size_t bytes) {
    char* r = p;
    p += (bytes + 255) & ~(size_t)255;
    return r;
  };
  unsigned* pp = (unsigned*)alloc((size_t)BB * 512 * 256 * 4);     // 33.5 MB
  unsigned* fw2 = (unsigned*)alloc((size_t)BB * 512 * GDIM * 4);   // 100.7 MB
  unsigned* wc2 = (unsigned*)alloc((size_t)256 * 1024 * 4);        // 1 MB
  unsigned* w4t = (unsigned*)alloc((size_t)128 * 1024 * 4);        // 0.5 MB (transposed)
  float* bias4 = (float*)alloc(1024 * 4);
  float* embb = (float*)alloc((size_t)NEMB * GDIM * 4);
  float* scoref = (float*)alloc(256 * 4);
  float* combw = (float*)alloc(256 * 34 * 4);
  float* combb = (float*)alloc(64 * 4);
  int* flag = (int*)alloc(256);
  int* bars = (int*)alloc(4096);
  float* Sx = (float*)alloc((size_t)2 * 64 * 4 * 4);
  float* ghxx = (float*)alloc((size_t)2 * 64 * GDIM * 4);
  float* gxpx = (float*)alloc((size_t)2 * 64 * 4 * GDIM * 4);
  int* bar1 = bars;

  TanhC tc;
  fit_tanh(tc.c);

  hipMemsetAsync(bars, 0, 4096, stream);
  k_sniff<<<1, 256, 0, stream>>>(fea, flag);
  k_wc<<<1024, 256, 0, stream>>>(i2h_w, gru_w_ih, wc2, flag);
  k_w4t<<<512, 256, 0, stream>>>(h2h_w, gru_w_hh, w4t, flag);
  k_bias4<<<4, 256, 0, stream>>>(h2h_b, gru_b_hh, bias4, flag);
  k_embb<<<90, 256, 0, stream>>>(gru_w_ih, gru_b_ih, embb, flag);
  k_cvt_f<<<1, 256, 0, stream>>>(score_w, scoref, 256, flag);
  k_comb<<<1, 256, 0, stream>>>(sg1_w, sg1_b, sg2_w, sg2_b, lg1_w, lg1_b, lg2_w, lg2_b, combw,
                                combb, flag);
  k_gemm<<<4096, 256, 0, stream>>>(fea, wc2, pp, fw2, flag);

  k_main_c4<<<256, 1024, 0, stream>>>(pp, fw2, targets, w4t, bias4, embb, scoref, combw, combb,
                                      d_out, flag, steps, tc, bar1, Sx, ghxx, gxpx);
}